// Round 10
// baseline (413.471 us; speedup 1.0000x reference)
//
#include <hip/hip_runtime.h>
#include <math.h>

// Problem constants (reference: B=8, C=32, O=32, H=256, W=256, K=5, pad=2)
constexpr int IMG_H = 256;
constexpr int IMG_W = 256;
constexpr int NB = 8;
constexpr int NC = 32;
constexpr int NO = 32;
constexpr int PLANE = IMG_H * IMG_W;          // 65536
constexpr int HALF = NB * NC * PLANE;         // 16,777,216 floats (64 MB)

// Wave-private tiling: each WAVE owns a 16x4 output tile; no __syncthreads.
// Halo region per wave: 8 rows x 24 cols, staged in wave-private LDS.
// Channels processed in PAIRS with a depth-2 register pipeline.
constexpr int WTW = 16;                       // wave tile width
constexpr int WTH = 4;                        // wave tile height
constexpr int RR = WTH + 4;                   // 8 region rows
constexpr int RC = 24;                        // region cols [w0-4, w0+20)
constexpr int RSB = RC * 8;                   // 192 B row stride ({P,V} f2/px)
constexpr int BUFB = RR * RSB;                // 1536 B per channel buffer
constexpr int WLDS = 4 * BUFB;                // 6144 B per wave (2 pairs)
constexpr int NWAVE = 4;                      // waves per block (independent)
constexpr int NT = NWAVE * 64;                // 256 threads
// grid: 16 x 64 wave-tiles per image x 8 images / 4 waves = 2048 blocks
constexpr int NBLK = (IMG_W / WTW) * (IMG_H / WTH) * NB / NWAVE;

#define EPSV 1e-20f

typedef float f4 __attribute__((ext_vector_type(4)));
typedef float f2 __attribute__((ext_vector_type(2)));

__device__ __forceinline__ float rcpf_(float x) { return __builtin_amdgcn_rcpf(x); }
__device__ __forceinline__ float softplusf_(float x) {
  return fmaxf(x, 0.0f) + log1pf(expf(-fabsf(x)));
}

// ws layout (floats): [0..31] wp, [32..831] sw (c-major, 25/ch),
// [832..1855] cwT[c][o] (transposed), [1856] sum(sw), [1857] sum(cw)
__global__ void weights_kernel(const float* __restrict__ wp_raw,
                               const float* __restrict__ sw_raw,
                               const float* __restrict__ cw_raw,
                               float* __restrict__ ws) {
  __shared__ float red[256];
  const int t = threadIdx.x;
  if (t < 32) ws[t] = softplusf_(wp_raw[t]);
  float ssum = 0.f;
  for (int i = t; i < NC * 25; i += 256) {
    float v = softplusf_(sw_raw[i]);
    ws[32 + i] = v;
    ssum += v;
  }
  float csum = 0.f;
  for (int i = t; i < NO * NC; i += 256) {
    float v = softplusf_(cw_raw[i]);
    int o = i >> 5, c = i & 31;
    ws[832 + c * NO + o] = v;  // transposed: [c][o]
    csum += v;
  }
  red[t] = ssum; __syncthreads();
  for (int off = 128; off; off >>= 1) { if (t < off) red[t] += red[t + off]; __syncthreads(); }
  const float S_sw = red[0];
  __syncthreads();
  red[t] = csum; __syncthreads();
  for (int off = 128; off; off >>= 1) { if (t < off) red[t] += red[t + off]; __syncthreads(); }
  if (t == 0) { ws[1856] = S_sw; ws[1857] = red[0]; }
}

// Pointwise gradient-propagation math. Requires cdv/cgv pre-zeroed for
// OOB pixels (then Pv = Vv = 0 follows algebraically, no NaN).
// NOTE (R9 lesson): keep the two-rcp formulation. The "one-rcp" rewrite
// gfd = (dr-dl)/2 * T * rcp(S + EPS*T) produces rcp(0)=inf when S=0 and
// T=1e-20 underflows/FTZs, then 0*inf = NaN at masked/boundary pixels.
// Here rcp(T)=1e20 stays finite and 0*1e20 = 0.
__device__ __forceinline__ void pointwise_pv(
    float dv, float cdv, float gxv, float cgv, int gw,
    float wpc, float inv_wp1, float& Pv, float& Vv) {
  // d_left = d with last col zeroed; d_right = d with first col zeroed
  float dl  = (gw == IMG_W - 1) ? 0.f : dv;
  float cdl = (gw == IMG_W - 1) ? 0.f : cdv;
  float dr  = (gw == 0) ? 0.f : dv;
  float cdr = (gw == 0) ? 0.f : cdv;
  float cfd = cdl * cdr;                                      // cgx_from_ds
  float height = (cdl * dl + cdr * dr) * rcpf_(cdl + cdr + EPSV);
  float gfd = (dr - dl) * 0.5f * rcpf_(height + EPSV);        // gx_from_ds
  float den = fmaf(wpc, cgv, cfd);                            // wp*cgx + cgx_from_ds
  float num = fmaf(wpc * cgv, gxv, cfd * gfd);
  float gprop = num * rcpf_(den + EPSV);
  float cprop = den * inv_wp1;
  Pv = cprop;
  Vv = cprop * gprop;
}

// ---------------------------------------------------------------------------
// Fully fused, barrier-free kernel with a DEPTH-2 channel pipeline.
//
// R5-R8 history: barrier-phased (167-200us) and barrier-free depth-1 (184us)
// all stall ~50% regardless of barriers/occupancy/conflicts/LDS-op-count.
// Remaining theory: per-channel global-load latency. Depth-1 gives a load
// only ~330-450 cyc of cover (one conv+acc) but ~40% of loads miss to HBM
// (~900 cyc; FETCH=153MB of 768MB issued). Fix: process channels in PAIRS
// with two register sets:
//   stage ch g (setA, loaded 1 pair-iter ago) -> buf[2q]
//   stage ch g+1 (setB)                       -> buf[2q+1]
//   issue 8 f4 loads for ch g+2 -> setA, g+3 -> setB   (MLP 8)
//   s_waitcnt lgkmcnt(0)      (wave-local; LDS is wave-private)
//   conv ch g, conv ch g+1 (50 b64 reads), rank-2 acc update
// A load now has a full pair-iteration (~900-1100 cyc) in flight before its
// vmcnt wait. 4 wave-private buffers (pair-alternating) keep read/write
// hazards two fences apart.
// (R9 attempted this but failed on an unrelated NaN in a math "optimization";
//  this round = R9 pipeline + R8's proven-correct math, isolating the
//  pipeline variable.)
// ---------------------------------------------------------------------------
__global__ __launch_bounds__(NT, 4) void fused_kernel(
    const float* __restrict__ dp, const float* __restrict__ cdp,
    const float* __restrict__ gxp, const float* __restrict__ cgxp,
    const float* __restrict__ ws, const float* __restrict__ bias,
    float* __restrict__ out) {
  __shared__ __align__(16) char shb[NWAVE * WLDS];  // 24,576 B

  const int t = threadIdx.x;
  const int wid = t >> 6;
  const int lane = t & 63;
  char* wbase = shb + wid * WLDS;

  // ---- tile mapping: XCD-striped images, row-major tile quads ----
  const int wg = blockIdx.x;
  const int virt = (wg & 7) * (NBLK / 8) + (wg >> 3);
  const int b = virt >> 8;
  const int rem = virt & 255;
  const int ty = rem >> 2;                   // 0..63
  const int qx = rem & 3;                    // 0..3
  const int tx = qx * 4 + wid;               // 0..15
  const int w0 = tx * WTW, h0 = ty * WTH;

  const float Ssw = ws[1856], Scw = ws[1857];
  const float epsS = EPSV * Ssw;
  const float oscale = rcpf_(Ssw) * rcpf_(Scw);

  // ---- staging geometry: 48 f4-tasks (8 rows x 6 quads), lanes 0..47 ----
  const bool sact = lane < 48;
  const int Rr = min(lane, 47) / 6;          // 0..7
  const int qq = min(lane, 47) - 6 * Rr;     // 0..5
  const int gh = h0 + Rr - 2;
  const int ghc = min(max(gh, 0), IMG_H - 1);
  const int gc0 = w0 - 4 + 4 * qq;           // true col of px 0 (may be OOB)
  const int gc0c = min(max(gc0, 0), IMG_W - 4);
  const int goff = ghc * IMG_W + gc0c;       // clamped, 16B aligned
  const bool rowv = (unsigned)gh < (unsigned)IMG_H;
  float msk[4];
  #pragma unroll
  for (int j = 0; j < 4; ++j)
    msk[j] = (rowv & ((unsigned)(gc0 + j) < (unsigned)IMG_W)) ? 1.f : 0.f;
  const int wb = Rr * RSB + qq * 32;         // LDS write byte (16B aligned)

  // ---- conv geometry ----
  const int x = lane & 15, y = lane >> 4;    // px in 16x4 tile
  const int cvb = y * RSB + (x + 2) * 8;     // tap(kr=0,kc=0) byte
  const int pixoff = (h0 + y) * IMG_W + (w0 + x);
  const int planebase = b * NC * PLANE;

  float accN[32], accD[32];
  #pragma unroll
  for (int o = 0; o < 32; ++o) { accN[o] = 0.f; accD[o] = 0.f; }

  // prologue: load channels 0 (setA) and 1 (setB)
  f4 dA, cA, gA, xA, dB, cB, gB, xB;
  if (sact) {
    const int p0 = planebase + goff;
    dA = *(const f4*)(dp + p0);  cA = *(const f4*)(cdp + p0);
    gA = *(const f4*)(gxp + p0); xA = *(const f4*)(cgxp + p0);
    const int p1 = p0 + PLANE;
    dB = *(const f4*)(dp + p1);  cB = *(const f4*)(cdp + p1);
    gB = *(const f4*)(gxp + p1); xB = *(const f4*)(cgxp + p1);
  }

  #pragma unroll 1
  for (int g = 0; g < NC; g += 2) {
    const int q = (g >> 1) & 1;              // buffer-pair select
    char* bufA = wbase + (2 * q) * BUFB;     // channel g
    char* bufB = wbase + (2 * q + 1) * BUFB; // channel g+1

    const float wpA = ws[g], wpB = ws[g + 1];
    const float invA = rcpf_(wpA + 1.0f), invB = rcpf_(wpB + 1.0f);

    // stage both channels (registers loaded one pair-iteration ago)
    if (sact) {
      float P[4], V[4];
      #pragma unroll
      for (int j = 0; j < 4; ++j)
        pointwise_pv(dA[j], cA[j] * msk[j], gA[j], xA[j] * msk[j], gc0 + j,
                     wpA, invA, P[j], V[j]);
      f4 w1; w1[0] = P[0]; w1[1] = V[0]; w1[2] = P[1]; w1[3] = V[1];
      f4 w2; w2[0] = P[2]; w2[1] = V[2]; w2[2] = P[3]; w2[3] = V[3];
      *(f4*)(bufA + wb) = w1;
      *(f4*)(bufA + wb + 16) = w2;
      #pragma unroll
      for (int j = 0; j < 4; ++j)
        pointwise_pv(dB[j], cB[j] * msk[j], gB[j], xB[j] * msk[j], gc0 + j,
                     wpB, invB, P[j], V[j]);
      f4 w3; w3[0] = P[0]; w3[1] = V[0]; w3[2] = P[1]; w3[3] = V[1];
      f4 w4; w4[0] = P[2]; w4[1] = V[2]; w4[2] = P[3]; w4[3] = V[3];
      *(f4*)(bufB + wb) = w3;
      *(f4*)(bufB + wb + 16) = w4;
    }

    // issue next pair's loads (8 f4 in flight across this whole iteration;
    // their vmcnt wait lands at NEXT iteration's stage = ~1000 cyc of cover)
    if ((g + 2 < NC) & sact) {
      const int pA = planebase + (g + 2) * PLANE + goff;
      dA = *(const f4*)(dp + pA);  cA = *(const f4*)(cdp + pA);
      gA = *(const f4*)(gxp + pA); xA = *(const f4*)(cgxp + pA);
      const int pB = pA + PLANE;
      dB = *(const f4*)(dp + pB);  cB = *(const f4*)(cdp + pB);
      gB = *(const f4*)(gxp + pB); xB = *(const f4*)(cgxp + pB);
    }

    // wave-local fence: this wave's LDS writes complete (no barrier needed;
    // LDS regions are wave-private and same-wave DS ops are in-order).
    asm volatile("s_waitcnt lgkmcnt(0)" ::: "memory");

    // depthwise 5x5 for both channels at this lane's pixel
    const char* bpA = bufA + cvb;
    const char* bpB = bufB + cvb;
    const float* swA = ws + 32 + g * 25;
    const float* swB = swA + 25;
    float DA = 0.f, NA = 0.f, DB = 0.f, NBv = 0.f;
    #pragma unroll
    for (int kr = 0; kr < 5; ++kr) {
      #pragma unroll
      for (int kc = 0; kc < 5; ++kc) {
        const int off = kr * RSB + kc * 8;
        const f2 pvA = *(const f2*)(bpA + off);
        const f2 pvB = *(const f2*)(bpB + off);
        const float wA = swA[kr * 5 + kc];
        const float wB = swB[kr * 5 + kc];
        DA  = fmaf(wA, pvA[0], DA);
        NA  = fmaf(wA, pvA[1], NA);
        DB  = fmaf(wB, pvB[0], DB);
        NBv = fmaf(wB, pvB[1], NBv);
      }
    }

    // rank-2 update of the 1x1-conv accumulators (static indices)
    const float* cwA = ws + 832 + g * NO;
    const float* cwB = cwA + NO;
    #pragma unroll
    for (int o = 0; o < 32; ++o) {
      accD[o] = fmaf(cwB[o], DB, fmaf(cwA[o], DA, accD[o]));
      accN[o] = fmaf(cwB[o], NBv, fmaf(cwA[o], NA, accN[o]));
    }
  }

  // epilogue: folded normalization + coalesced store (16-wide rows = 64 B)
  //   gx[o]  = accN[o]/(accD[o] + EPS*Ssw) + bias[o]
  //   cgx[o] = accD[o]/(Ssw*Scw)
  const int ob = b * NO * PLANE + pixoff;
  #pragma unroll
  for (int o = 0; o < 32; ++o) {
    const float g = fmaf(accN[o], rcpf_(accD[o] + epsS), bias[o]);
    const float cg = accD[o] * oscale;
    out[ob + o * PLANE] = g;
    out[HALF + ob + o * PLANE] = cg;
  }
}

extern "C" void kernel_launch(void* const* d_in, const int* in_sizes, int n_in,
                              void* d_out, int out_size, void* d_ws, size_t ws_size,
                              hipStream_t stream) {
  const float* dp   = (const float*)d_in[0];
  const float* cdp  = (const float*)d_in[1];
  const float* gxp  = (const float*)d_in[2];
  const float* cgxp = (const float*)d_in[3];
  const float* wp   = (const float*)d_in[4];
  const float* sw   = (const float*)d_in[5];
  const float* cw   = (const float*)d_in[6];
  const float* bias = (const float*)d_in[7];
  float* out = (float*)d_out;
  float* ws  = (float*)d_ws;

  weights_kernel<<<1, 256, 0, stream>>>(wp, sw, cw, ws);
  fused_kernel<<<NBLK, NT, 0, stream>>>(dp, cdp, gxp, cgxp, ws, bias, out);
}

// Round 11
// 396.726 us; speedup vs baseline: 1.0422x; 1.0422x over previous
//
#include <hip/hip_runtime.h>
#include <math.h>

// Problem constants (reference: B=8, C=32, O=32, H=256, W=256, K=5, pad=2)
constexpr int IMG_H = 256;
constexpr int IMG_W = 256;
constexpr int NB = 8;
constexpr int NC = 32;
constexpr int NO = 32;
constexpr int PLANE = IMG_H * IMG_W;          // 65536
constexpr int HALF = NB * NC * PLANE;         // 16,777,216 floats (64 MB)

// Fused tiling (R5 geometry): block = one (b, 16x32 tile), thread = one px.
// One channel per barrier phase, 2 LDS buffers. {P,V} interleaved per px.
constexpr int TW = 16;                        // tile width
constexpr int TH = 32;                        // tile height
constexpr int NT = TW * TH;                   // 512 threads
constexpr int RR = TH + 4;                    // 36 region rows
constexpr int RC = 24;                        // stored cols [w0-4, w0+20)
constexpr int RSB = RC * 8;                   // 192 B row stride ({P,V} f2/px)
constexpr int BUFB = RR * RSB;                // 6912 B per channel buffer
constexpr int NTASK = RR * 12;                // 432 staging tasks (2 px each)
constexpr int TILES = (IMG_W / TW) * (IMG_H / TH);  // 128 tiles per image

#define EPSV 1e-20f

typedef float f4 __attribute__((ext_vector_type(4)));
typedef float f2 __attribute__((ext_vector_type(2)));

__device__ __forceinline__ float rcpf_(float x) { return __builtin_amdgcn_rcpf(x); }
__device__ __forceinline__ float softplusf_(float x) {
  return fmaxf(x, 0.0f) + log1pf(expf(-fabsf(x)));
}

// ws layout (floats): [0..31] wp, [32..831] sw (c-major, 25/ch),
// [832..1855] cwT[c][o] (transposed), [1856] sum(sw), [1857] sum(cw)
__global__ void weights_kernel(const float* __restrict__ wp_raw,
                               const float* __restrict__ sw_raw,
                               const float* __restrict__ cw_raw,
                               float* __restrict__ ws) {
  __shared__ float red[256];
  const int t = threadIdx.x;
  if (t < 32) ws[t] = softplusf_(wp_raw[t]);
  float ssum = 0.f;
  for (int i = t; i < NC * 25; i += 256) {
    float v = softplusf_(sw_raw[i]);
    ws[32 + i] = v;
    ssum += v;
  }
  float csum = 0.f;
  for (int i = t; i < NO * NC; i += 256) {
    float v = softplusf_(cw_raw[i]);
    int o = i >> 5, c = i & 31;
    ws[832 + c * NO + o] = v;  // transposed: [c][o]
    csum += v;
  }
  red[t] = ssum; __syncthreads();
  for (int off = 128; off; off >>= 1) { if (t < off) red[t] += red[t + off]; __syncthreads(); }
  const float S_sw = red[0];
  __syncthreads();
  red[t] = csum; __syncthreads();
  for (int off = 128; off; off >>= 1) { if (t < off) red[t] += red[t + off]; __syncthreads(); }
  if (t == 0) { ws[1856] = S_sw; ws[1857] = red[0]; }
}

// Pointwise gradient-propagation math. Requires cdv/cgv pre-zeroed for
// OOB pixels (then Pv = Vv = 0 algebraically, no NaN).
// Two changes vs the reference chain, both exact-to-fp32-tolerance:
//  - P = den*inv_wp1 (unchanged).
//  - V = num*inv_wp1 replaces (den*inv_wp1)*(num*rcp(den+eps)): the factor
//    den/(den+eps) is 1 unless den < ~1e-13, and then |num| <= den*O(1) so
//    the absolute error is < 1e-13. den=0 => num=0 => V=0 exactly. No
//    rcp(0)=inf path exists (R9 lesson: every rcp argument here is >= EPSV).
__device__ __forceinline__ void pointwise_pv(
    float dv, float cdv, float gxv, float cgv, int gw,
    float wpc, float inv_wp1, float& Pv, float& Vv) {
  // d_left = d with last col zeroed; d_right = d with first col zeroed
  float dl  = (gw == IMG_W - 1) ? 0.f : dv;
  float cdl = (gw == IMG_W - 1) ? 0.f : cdv;
  float dr  = (gw == 0) ? 0.f : dv;
  float cdr = (gw == 0) ? 0.f : cdv;
  float cfd = cdl * cdr;                                      // cgx_from_ds
  float height = (cdl * dl + cdr * dr) * rcpf_(cdl + cdr + EPSV);
  float gfd = (dr - dl) * 0.5f * rcpf_(height + EPSV);        // gx_from_ds
  float den = fmaf(wpc, cgv, cfd);                            // wp*cgx + cfd
  float num = fmaf(wpc * cgv, gxv, cfd * gfd);
  Pv = den * inv_wp1;
  Vv = num * inv_wp1;
}

// ---------------------------------------------------------------------------
// Fused kernel, R5 structure + packed-f2 math + register-pressure fix.
//
// Cross-round regularity (R5-R10): dur = VALU-busy + ~100us, with busy itself
// 2-2.5x the arithmetic floor, VGPR_Count=64 reported despite 64 accumulator
// floats alone, and occupancy pinned at ~37% in every variant. Theory: the
// compiler moved accN/accD to AGPRs (unified file; rocprof shows arch VGPRs
// only) -> v_accvgpr_read/write around every acc FMA (instruction inflation)
// and ~128 total regs/lane (4 waves/SIMD residency cap).
// Fixes in this version:
//  - f2-packed conv and acc: {P,V} interleaved in LDS; dn += pv*w (25 pk-FMA
//    per channel, was 50 FMA); accDN[o] += dn*cw (32 pk-FMA, was 64 FMA).
//  - one fewer rcp per pointwise eval (V = num*inv_wp1).
//  - __launch_bounds__(512,3): VGPR cap 170 so accumulators stay in arch
//    VGPRs (predict VGPR_Count ~110-150 — the adjudicating counter).
// ---------------------------------------------------------------------------
__global__ __launch_bounds__(NT, 3) void fused_kernel(
    const float* __restrict__ dp, const float* __restrict__ cdp,
    const float* __restrict__ gxp, const float* __restrict__ cgxp,
    const float* __restrict__ ws, const float* __restrict__ bias,
    float* __restrict__ out) {
  __shared__ __align__(16) char shb[2 * BUFB];  // 13,824 B

  const int t = threadIdx.x;

  // XCD-aware swizzle: 1024 blocks; image k -> XCD k.
  const int wg = blockIdx.x;
  const int virt = (wg & 7) * TILES + (wg >> 3);
  const int b = virt >> 7;                       // /128 tiles
  const int tile = virt & (TILES - 1);
  const int tx = tile & 15, ty = tile >> 4;      // 16 x 8 tile grid
  const int w0 = tx * TW, h0 = ty * TH;

  const float Ssw = ws[1856], Scw = ws[1857];
  const float epsS = EPSV * Ssw;
  const float oscale = rcpf_(Ssw) * rcpf_(Scw);

  // ---- staging geometry: 432 tasks (36 rows x 12 col-pairs), t<432 ----
  const bool sact = t < NTASK;
  const int task = min(t, NTASK - 1);
  const int R = task / 12;
  const int hq = task - R * 12;
  const int gh = h0 + R - 2;
  const int ghc = min(max(gh, 0), IMG_H - 1);
  const int g0 = w0 - 4 + 2 * hq;
  const int g0c = min(max(g0, 0), IMG_W - 2);    // even => 8B aligned
  const int goff = ghc * IMG_W + g0c;
  const bool rowv = (unsigned)gh < (unsigned)IMG_H;
  const float m0 = (rowv & ((unsigned)g0 < (unsigned)IMG_W)) ? 1.f : 0.f;
  const float m1 = (rowv & ((unsigned)(g0 + 1) < (unsigned)IMG_W)) ? 1.f : 0.f;
  const int wb = R * RSB + hq * 16;              // 16B-aligned f4 write

  // ---- conv geometry ----
  const int x = t & (TW - 1);
  const int r = t >> 4;                          // 0..31
  const int cvb = r * RSB + (x + 2) * 8;         // tap(0,0) byte
  const int pixoff = (h0 + r) * IMG_W + (w0 + x);
  const int planebase = b * NC * PLANE;

  // packed accumulators: accDN[o] = {sum cw*D, sum cw*N}
  f2 accDN[32];
  #pragma unroll
  for (int o = 0; o < 32; ++o) accDN[o] = f2{0.f, 0.f};

  // prologue: load channel 0
  f2 vd, vc, vg, vx;
  if (sact) {
    vd = *(const f2*)(dp + planebase + goff);
    vc = *(const f2*)(cdp + planebase + goff);
    vg = *(const f2*)(gxp + planebase + goff);
    vx = *(const f2*)(cgxp + planebase + goff);
  }

  #pragma unroll 1
  for (int c = 0; c < NC; ++c) {
    char* buf = shb + (c & 1) * BUFB;
    const float wpc = ws[c];
    const float inv_wp1 = rcpf_(wpc + 1.0f);

    // stage: pointwise 2 px -> one f4 {P0,V0,P1,V1}
    if (sact) {
      float P0, V0, P1, V1;
      pointwise_pv(vd[0], vc[0] * m0, vg[0], vx[0] * m0, g0,
                   wpc, inv_wp1, P0, V0);
      pointwise_pv(vd[1], vc[1] * m1, vg[1], vx[1] * m1, g0 + 1,
                   wpc, inv_wp1, P1, V1);
      f4 w; w[0] = P0; w[1] = V0; w[2] = P1; w[3] = V1;
      *(f4*)(buf + wb) = w;
    }

    __syncthreads();  // channel c staged

    // prefetch channel c+1 AFTER the barrier (covered by conv+acc; its
    // vmcnt wait lands at next iteration's stage, not at this barrier).
    if ((c + 1 < NC) & sact) {
      const int pb = planebase + (c + 1) * PLANE + goff;
      vd = *(const f2*)(dp + pb);
      vc = *(const f2*)(cdp + pb);
      vg = *(const f2*)(gxp + pb);
      vx = *(const f2*)(cgxp + pb);
    }

    // depthwise 5x5, packed: dn = {D_c, N_c}
    const char* bp = buf + cvb;
    const float* swc = ws + 32 + c * 25;
    f2 dn = f2{0.f, 0.f};
    #pragma unroll
    for (int kr = 0; kr < 5; ++kr) {
      #pragma unroll
      for (int kc = 0; kc < 5; ++kc) {
        const f2 pv = *(const f2*)(bp + kr * RSB + kc * 8);
        dn += pv * swc[kr * 5 + kc];             // v_pk_fma_f32
      }
    }

    // rank-1 update, packed (static indices)
    const float* cwc = ws + 832 + c * NO;
    #pragma unroll
    for (int o = 0; o < 32; ++o)
      accDN[o] += dn * cwc[o];                   // v_pk_fma_f32

    // next iteration stages the OTHER buffer; writes to THIS buffer occur
    // two iterations later, fenced by the next iteration's barrier.
  }

  // epilogue: folded normalization + coalesced store
  //   gx[o]  = N/(D + EPS*Ssw) + bias[o];  cgx[o] = D/(Ssw*Scw)
  const int ob = b * NO * PLANE + pixoff;
  #pragma unroll
  for (int o = 0; o < 32; ++o) {
    const float D = accDN[o][0], N = accDN[o][1];
    out[ob + o * PLANE] = fmaf(N, rcpf_(D + epsS), bias[o]);
    out[HALF + ob + o * PLANE] = D * oscale;
  }
}

extern "C" void kernel_launch(void* const* d_in, const int* in_sizes, int n_in,
                              void* d_out, int out_size, void* d_ws, size_t ws_size,
                              hipStream_t stream) {
  const float* dp   = (const float*)d_in[0];
  const float* cdp  = (const float*)d_in[1];
  const float* gxp  = (const float*)d_in[2];
  const float* cgxp = (const float*)d_in[3];
  const float* wp   = (const float*)d_in[4];
  const float* sw   = (const float*)d_in[5];
  const float* cw   = (const float*)d_in[6];
  const float* bias = (const float*)d_in[7];
  float* out = (float*)d_out;
  float* ws  = (float*)d_ws;

  weights_kernel<<<1, 256, 0, stream>>>(wp, sw, cw, ws);
  fused_kernel<<<TILES * NB, NT, 0, stream>>>(dp, cdp, gxp, cgxp, ws, bias,
                                              out);
}